// Round 3
// baseline (669.013 us; speedup 1.0000x reference)
//
#include <hip/hip_runtime.h>

// Problem constants (fixed by reference)
constexpr int N_  = 10000;   // nodes (< 65536 -> u16 src)
constexpr int E_  = 320000;  // edges
constexpr int F1  = 33;      // input features
constexpr int H   = 32;      // hidden
constexpr int G   = 64;      // graphs
constexpr int CAP = 96;      // padded CSR slots/node (deg~Poisson(32), P(overflow)~1e-18/node)

// Single plain-launch fused kernel. 640 blocks x 256 threads.
// __launch_bounds__(256,8) -> VGPR <= 64 -> 8 blocks/CU capacity = 2048 slots,
// so all 640 blocks are hardware-co-resident (LDS 12.9KB/block, 160KB pool).
// Custom agent-scope sense-reversing barrier replaces grid.sync (no cooperative
// API: no validator, no coop-launch graph overhead).
constexpr int GRID  = 640;
constexpr int BT    = 256;
constexpr int NTASK = N_ / 8;   // 1250 block-tasks of 8 nodes (4 waves x 2 nodes)

// round-to-nearest-even f32 -> bf16 (low 16 bits)
__device__ __forceinline__ unsigned bf16r(float x) {
    unsigned u = __float_as_uint(x);
    return (u + 0x7FFFu + ((u >> 16) & 1u)) >> 16;
}

struct Prm {
    const float* x; const int* ei; const float* ea; const int* batch;
    const float* A1; const float* B1; const float* R1; const float* z1;
    const float* A2; const float* B2; const float* R2; const float* z2;
    const float* A3; const float* B3; const float* R3; const float* z3;
    const float* l1w; const float* l1b; const float* l2w; const float* l2b;
    int* bar; int* counts; int* startsP; unsigned* meta;
    unsigned* UVa; float* Ra; unsigned* UVb; float* Rb; float* Hs;
    float* out;
};

// ---- global barrier: sense-reversing, agent scope, bounded spin ----
__device__ __forceinline__ void gbar(int* bar) {
    __syncthreads();
    if (threadIdx.x == 0) {
        __threadfence();   // release: push this CU's dirty lines device-wide
        int gen = __hip_atomic_load(&bar[1], __ATOMIC_RELAXED, __HIP_MEMORY_SCOPE_AGENT);
        int a = __hip_atomic_fetch_add(&bar[0], 1, __ATOMIC_ACQ_REL, __HIP_MEMORY_SCOPE_AGENT);
        if (a == GRID - 1) {
            __hip_atomic_store(&bar[0], 0, __ATOMIC_RELAXED, __HIP_MEMORY_SCOPE_AGENT);
            __hip_atomic_store(&bar[1], gen + 1, __ATOMIC_RELEASE, __HIP_MEMORY_SCOPE_AGENT);
        } else {
            int spins = 0;
            while (__hip_atomic_load(&bar[1], __ATOMIC_RELAXED, __HIP_MEMORY_SCOPE_AGENT) == gen) {
                __builtin_amdgcn_s_sleep(1);
                if (++spins > (1 << 22)) break;   // safety valve: fail loud, don't hang
            }
        }
        __threadfence();   // acquire: invalidate stale lines before next phase
    }
    __syncthreads();
}

// ---- phase: build padded CSR (node-major meta) + layer-1 UV/R + graph starts ----
__device__ __forceinline__ void build(const Prm& p) {
    const int tid = threadIdx.x, bid = blockIdx.x;
    for (int e = bid * BT + tid; e < E_; e += GRID * BT) {
        int s = p.ei[e];
        int d = p.ei[E_ + e];
        int pos = atomicAdd(&p.counts[d], 1);
        p.meta[(size_t)d * CAP + pos] = (unsigned)s | (bf16r(p.ea[e]) << 16);
    }
    const int grp = tid >> 5, f = tid & 31;   // 8 node-groups x 32 features
    for (int t = bid; t < NTASK; t += GRID) {
        int node = t * 8 + grp;               // N_ % 8 == 0 -> always valid
        if (f == 0) {                         // graph-boundary detection (batch sorted)
            int b = p.batch[node];
            int bp = (node == 0) ? -1 : p.batch[node - 1];
            if (b != bp) p.startsP[b] = node + 1;
        }
        float u = 0.f, v = 0.f, r = p.z1[f];
        const float* xr = p.x + (size_t)node * F1;
        #pragma unroll
        for (int k = 0; k < F1; ++k) {
            float xv = xr[k];
            u = fmaf(xv, p.A1[k * H + f], u);
            v = fmaf(xv, p.B1[k * H + f], v);
            r = fmaf(xv, p.R1[k * H + f], r);
        }
        p.UVa[(node << 5) | f] = bf16r(u) | (bf16r(v) << 16);  // node-major, coalesced
        p.Ra [(node << 5) | f] = r;
    }
}

// ---- phase: aggregation (+ fused next-layer precompute for LAYER 1,2) ----
// Wave = 2 nodes x 32 features. Gather UV[src][0..31] = one coalesced 128B row
// per half-wave. meta read ONCE per layer (node-major rows, 128B per half-wave).
template<int LAYER>
__device__ __forceinline__ void aggpre(const Prm& p, float (*wL)[H * H],
        const unsigned* __restrict__ UVin, const float* __restrict__ Rin,
        unsigned* __restrict__ UVout, float* __restrict__ Rout) {
    const int tid = threadIdx.x;
    const float* zb = (LAYER == 1) ? p.z2 : p.z3;
    if (LAYER == 1) {
        for (int i = tid; i < H * H; i += BT) {
            wL[0][i] = p.A2[i]; wL[1][i] = p.B2[i]; wL[2][i] = p.R2[i];
        }
    } else if (LAYER == 2) {
        for (int i = tid; i < H * H; i += BT) {
            wL[0][i] = p.A3[i]; wL[1][i] = p.B3[i]; wL[2][i] = p.R3[i];
        }
    }
    if (LAYER < 3) __syncthreads();

    const int lane = tid & 63, wav = tid >> 6;
    const int f = lane & 31;
    const float zf = (LAYER < 3) ? zb[f] : 0.f;

    for (int t = blockIdx.x; t < NTASK; t += GRID) {
        const int n = t * 8 + wav * 2 + (lane >> 5);   // node of this half-wave
        const int dg = p.counts[n];
        const unsigned* mrow = p.meta + (size_t)n * CAP;
        unsigned m0 = mrow[f], m1 = mrow[32 + f], m2 = mrow[64 + f];
        float r = Rin[(n << 5) | f];
        float acc = 0.f;
        auto slot = [&](unsigned mreg, int j) {
            unsigned mv = __shfl(mreg, (lane & 32) | (j & 31), 64);
            unsigned src = min(mv & 0xFFFFu, (unsigned)(N_ - 1));
            unsigned w = UVin[(src << 5) | f];          // coalesced 128B per half-wave
            float tv = fmaf(__uint_as_float(mv & 0xFFFF0000u),   // a (bf16 hi)
                            __uint_as_float(w << 16),            // u
                            __uint_as_float(w & 0xFFFF0000u));   // v
            if (j < dg) acc += tv;
        };
        #pragma unroll
        for (int j = 0; j < 32; ++j) slot(m0, j);
        #pragma unroll
        for (int j = 32; j < 48; ++j) slot(m1, j);
        if (__any(dg > 48)) {                           // rare tail (P(dg>48) ~ 0.2%/node)
            #pragma unroll
            for (int j = 48; j < 64; ++j) slot(m1, j);
        }
        if (__any(dg > 64)) {
            #pragma unroll
            for (int j = 64; j < 96; ++j) slot(m2, j);
        }
        float h = fmaxf(r + acc, 0.f);                  // h[n][f], per-lane

        if (LAYER == 3) {
            p.Hs[(n << 5) | f] = h;
        } else {
            // fused next-layer precompute: needs only this node's h (in half-wave regs)
            float u = 0.f, v = 0.f, rn = zf;
            #pragma unroll
            for (int k = 0; k < H; ++k) {
                float hk = __shfl(h, k, 32);
                u  = fmaf(hk, wL[0][k * H + f], u);
                v  = fmaf(hk, wL[1][k * H + f], v);
                rn = fmaf(hk, wL[2][k * H + f], rn);
            }
            UVout[(n << 5) | f] = bf16r(u) | (bf16r(v) << 16);
            Rout [(n << 5) | f] = rn;
        }
    }
}

// ---- phase: per-graph pooling + readout (blocks 0..63) ----
__device__ __forceinline__ void pool(const Prm& p, int* sst, float* gpl) {
    const int tid = threadIdx.x;
    const int g = blockIdx.x;
    if (tid < G) sst[tid] = p.startsP[tid];
    __syncthreads();
    int sp = sst[g];
    int s0 = 0, e0 = 0;
    if (sp != 0) {
        s0 = sp - 1;
        e0 = N_;
        for (int j = g + 1; j < G; ++j)
            if (sst[j]) { e0 = sst[j] - 1; break; }
    }
    int f = tid >> 3, oct = tid & 7;
    float sum = 0.f, mx = 0.f;
    for (int n = s0 + oct; n < e0; n += 8) {
        float w = p.Hs[(n << 5) | f];
        sum += w;
        mx = fmaxf(mx, w);
    }
    sum += __shfl_xor(sum, 1); mx = fmaxf(mx, __shfl_xor(mx, 1));
    sum += __shfl_xor(sum, 2); mx = fmaxf(mx, __shfl_xor(mx, 2));
    sum += __shfl_xor(sum, 4); mx = fmaxf(mx, __shfl_xor(mx, 4));
    if (oct == 0) {
        float c = fmaxf((float)(e0 - s0), 1.0f);
        gpl[f] = sum;
        gpl[H + f] = sum / c;
        gpl[2 * H + f] = mx;
    }
    __syncthreads();
    if (tid < 32) {
        float hacc = p.l1b[tid];
        #pragma unroll
        for (int k = 0; k < H; ++k) {
            hacc = fmaf(gpl[k],         p.l1w[k * H + tid], hacc);
            hacc = fmaf(gpl[H + k],     p.l1w[(H + k) * H + tid], hacc);
            hacc = fmaf(gpl[2 * H + k], p.l1w[(2 * H + k) * H + tid], hacc);
        }
        float hid = fmaxf(hacc, 0.f);
        float p0 = hid * p.l2w[tid * 2 + 0];
        float p1 = hid * p.l2w[tid * 2 + 1];
        #pragma unroll
        for (int o = 16; o; o >>= 1) {
            p0 += __shfl_xor(p0, o, 32);
            p1 += __shfl_xor(p1, o, 32);
        }
        if (tid == 0) {
            float l0 = p0 + p.l2b[0], l1 = p1 + p.l2b[1];
            float m = fmaxf(l0, l1);
            float lse = m + logf(expf(l0 - m) + expf(l1 - m));
            p.out[g * 2 + 0] = l0 - lse;
            p.out[g * 2 + 1] = l1 - lse;
        }
    }
}

// ---- fused kernel: build -> agg1+pre2 -> agg2+pre3 -> agg3 -> pool ----
__global__ __launch_bounds__(BT, 8) void k_fused(Prm p) {
    __shared__ float wL[3][H * H];   // 12 KB next-layer weights
    __shared__ int   sst[G];
    __shared__ float gpl[3 * H];

    build(p);
    gbar(p.bar);
    aggpre<1>(p, wL, p.UVa, p.Ra, p.UVb, p.Rb);
    gbar(p.bar);
    aggpre<2>(p, wL, p.UVb, p.Rb, p.UVa, p.Ra);
    gbar(p.bar);
    aggpre<3>(p, wL, p.UVa, p.Ra, p.UVb, p.Rb);
    gbar(p.bar);
    if (blockIdx.x < G) pool(p, sst, gpl);
}

// ---------------- launch ----------------

extern "C" void kernel_launch(void* const* d_in, const int* in_sizes, int n_in,
                              void* d_out, int out_size, void* d_ws, size_t ws_size,
                              hipStream_t stream) {
    const float* x      = (const float*)d_in[0];
    const int*   ei     = (const int*)  d_in[1];
    const float* ea     = (const float*)d_in[2];
    const int*   batch  = (const int*)  d_in[3];
    const float* nn_w1  = (const float*)d_in[4];
    const float* nn_b1  = (const float*)d_in[5];
    const float* root1  = (const float*)d_in[6];
    const float* bias1  = (const float*)d_in[7];
    const float* nn_w2  = (const float*)d_in[8];
    const float* nn_b2  = (const float*)d_in[9];
    const float* root2  = (const float*)d_in[10];
    const float* bias2  = (const float*)d_in[11];
    const float* nn_w3  = (const float*)d_in[12];
    const float* nn_b3  = (const float*)d_in[13];
    const float* root3  = (const float*)d_in[14];
    const float* bias3  = (const float*)d_in[15];
    const float* lin1_w = (const float*)d_in[16];
    const float* lin1_b = (const float*)d_in[17];
    const float* lin2_w = (const float*)d_in[18];
    const float* lin2_b = (const float*)d_in[19];
    float* out = (float*)d_out;

    char* ws = (char*)d_ws;
    size_t off = 0;
    auto alloc = [&](size_t bytes) -> void* {
        void* p = ws + off;
        off += (bytes + 255) & ~(size_t)255;
        return p;
    };
    // zero-init chunk: bar | counts | startsP (one small memset)
    const size_t zbytes = 64 + N_ * sizeof(int) + G * sizeof(int);
    char* zchunk = (char*)alloc(zbytes);
    int* bar     = (int*)zchunk;
    int* counts  = (int*)(zchunk + 64);
    int* startsP = (int*)(zchunk + 64 + N_ * sizeof(int));
    unsigned* meta = (unsigned*)alloc((size_t)N_ * CAP * sizeof(unsigned)); // 3.84 MB
    unsigned* UVa = (unsigned*)alloc((size_t)N_ * H * sizeof(unsigned));
    float*    Ra  = (float*)   alloc((size_t)N_ * H * sizeof(float));
    unsigned* UVb = (unsigned*)alloc((size_t)N_ * H * sizeof(unsigned));
    float*    Rb  = (float*)   alloc((size_t)N_ * H * sizeof(float));
    float*    Hs  = (float*)   alloc((size_t)N_ * H * sizeof(float));

    Prm prm{ x, ei, ea, batch,
             nn_w1, nn_b1, root1, bias1,
             nn_w2, nn_b2, root2, bias2,
             nn_w3, nn_b3, root3, bias3,
             lin1_w, lin1_b, lin2_w, lin2_b,
             bar, counts, startsP, meta, UVa, Ra, UVb, Rb, Hs, out };

    hipMemsetAsync(zchunk, 0, zbytes, stream);
    k_fused<<<GRID, BT, 0, stream>>>(prm);
}